// Round 5
// baseline (169.426 us; speedup 1.0000x reference)
//
#include <hip/hip_runtime.h>
#include <stdint.h>

#define B_ROWS 8192
#define H_DIM 1024
#define L_DIM 1024
#define NH 5

typedef float f32x4 __attribute__((ext_vector_type(4)));
typedef int i32x4 __attribute__((ext_vector_type(4)));
typedef int i32x8 __attribute__((ext_vector_type(8)));

typedef const __attribute__((address_space(1))) unsigned int* gas_uint_ptr;
typedef __attribute__((address_space(3))) unsigned int* las_uint_ptr;

__device__ __forceinline__ void load_lds16(const void* gsrc, void* ldst) {
  __builtin_amdgcn_global_load_lds((gas_uint_ptr)(uintptr_t)gsrc,
                                   (las_uint_ptr)(uintptr_t)ldst, 16, 0, 0);
}

// pack 4 fp32 -> 4 OCP e4m3 in one uint (byte i = element i)
__device__ __forceinline__ unsigned int pack_fp8x4(float4 f) {
  int r = __builtin_amdgcn_cvt_pk_fp8_f32(f.x, f.y, 0, false);
  r = __builtin_amdgcn_cvt_pk_fp8_f32(f.z, f.w, r, true);
  return (unsigned int)r;
}

// ---- kernel 1: bucket rows by group (LDS-aggregated: 5 global atomics/block) ----
__global__ void k_bucket(const int* __restrict__ group, int* __restrict__ cnt,
                         int* __restrict__ rowlist) {
  __shared__ int lcnt[NH];
  __shared__ int lbase[NH];
  int t = threadIdx.x;
  if (t < NH) lcnt[t] = 0;
  __syncthreads();
  int b = blockIdx.x * 256 + t;
  int g = group[b];
  int lpos = -1;
  if (g < NH) lpos = atomicAdd(&lcnt[g], 1);
  __syncthreads();
  if (t < NH) lbase[t] = atomicAdd(&cnt[t], lcnt[t]);
  __syncthreads();
  if (g < NH) rowlist[g * B_ROWS + lbase[g] + lpos] = b;
}

// ---- kernel 2: fused streaming convert (fp32 -> fp8 e4m3) ----
// blocks [0,512):    W fp32->fp8, grid-stride, 10 float4/thread
// blocks [512,1536): 8 rows/block; g==5 -> fill out with label, else hidden->fp8 Hb
__global__ void k_conv(const float* __restrict__ hidden, const float* __restrict__ W,
                       const int* __restrict__ group, const int* __restrict__ labels,
                       unsigned char* __restrict__ Hb, unsigned char* __restrict__ Wb,
                       float* __restrict__ out) {
  const int blk = blockIdx.x;
  const int t = threadIdx.x;
  if (blk < 512) {
    const float4* src = (const float4*)W;
    unsigned int* dst = (unsigned int*)Wb;
#pragma unroll
    for (int i = 0; i < 10; i++) {
      int idx = (i * 512 + blk) * 256 + t;   // 512*256*10 = 1,310,720 float4 = all of W
      dst[idx] = pack_fp8x4(src[idx]);
    }
  } else {
    const int rb = (blk - 512) * 8;
    int gs[8];
#pragma unroll
    for (int r = 0; r < 8; r++) gs[r] = group[rb + r];
#pragma unroll
    for (int r = 0; r < 8; r++) {
      int row = rb + r;
      if (gs[r] == NH) {
        float v = (float)labels[row];
        ((float4*)(out + (size_t)row * L_DIM))[t] = make_float4(v, v, v, v);
      } else {
        float4 h = ((const float4*)(hidden + (size_t)row * H_DIM))[t];
        ((unsigned int*)(Hb + (size_t)row * H_DIM))[t] = pack_fp8x4(h);
      }
    }
  }
}

// ---- kernel 3: bucketed MX-fp8 MFMA GEMM, double-buffered LDS, rowlist-indirect A ----
// 128x128 tile, BK=128 (fp8: 16KB per matrix per buffer — same staging bytes/iter
// as bf16 BK=64, but half the barriers and 2x the MFMA rate via the scaled path).
// 4 waves (2x2), each wave 4x4 frags of 16x16x128 f8f6f4 (fp8/fp8, scale=1.0).
// LDS XOR-swizzle on 16B chunks: col cl holds global col cl ^ (row&7).
__global__ __launch_bounds__(256, 2)
void k_gemm(const unsigned char* __restrict__ Hb, const unsigned char* __restrict__ Wb,
            const float* __restrict__ bias, const int* __restrict__ cnt,
            const int* __restrict__ rowlist, float* __restrict__ out) {
  const int head = blockIdx.z;
  const int cntg = cnt[head];
  const int rowbase = blockIdx.y * 128;
  if (rowbase >= cntg) return;
  const int n0 = blockIdx.x * 128;

  __shared__ __align__(16) unsigned char As[2][128 * 128];
  __shared__ __align__(16) unsigned char Bs[2][128 * 128];

  const int t = threadIdx.x;
  const int wave = t >> 6, lane = t & 63;
  const int quad = lane >> 4, c16 = lane & 15;
  const int wm = (wave & 1) * 64, wn = (wave >> 1) * 64;

  const unsigned char* Wg = Wb + (size_t)head * L_DIM * H_DIM;
  const int* rl = rowlist + head * B_ROWS;

  // per-thread staging sources (loop-invariant; +kt bytes per iteration)
  const unsigned char* srcA[4];
  const unsigned char* srcB[4];
  int ldso[4];
#pragma unroll
  for (int p = 0; p < 4; p++) {
    int c = p * 256 + t;                   // 16B chunk id 0..1023
    int row = c >> 3;
    int ks = ((c & 7) ^ (row & 7)) * 16;   // XOR-swizzled source col (bytes)
    int idx = rowbase + row;
    idx = idx < cntg ? idx : cntg - 1;     // clamp into valid rowlist entries
    int rA = rl[idx];
    srcA[p] = Hb + (size_t)rA * H_DIM + ks;
    srcB[p] = Wg + (size_t)(n0 + row) * H_DIM + ks;
    ldso[p] = c * 16;                      // lane-linear LDS dst (bytes)
  }

  f32x4 acc[4][4] = {};
  const int sc1 = 0x7F7F7F7F;              // e8m0 127 = x1.0, replicated all bytes

  // prologue: stage K-tile 0
#pragma unroll
  for (int p = 0; p < 4; p++) {
    load_lds16(srcA[p], &As[0][ldso[p]]);
    load_lds16(srcB[p], &Bs[0][ldso[p]]);
  }
  __syncthreads();

  for (int kt = 0; kt < H_DIM; kt += 128) {
    const int cur = (kt >> 7) & 1;
    if (kt + 128 < H_DIM) {
      const int nxt = cur ^ 1;
#pragma unroll
      for (int p = 0; p < 4; p++) {
        load_lds16(srcA[p] + kt + 128, &As[nxt][ldso[p]]);
        load_lds16(srcB[p] + kt + 128, &Bs[nxt][ldso[p]]);
      }
    }
    {
      const int sw = c16 & 7;              // row&7 == c16&7 for all frag rows
      i32x8 af[4], bf[4];
#pragma unroll
      for (int i = 0; i < 4; i++) {
        const unsigned char* rbase = &As[cur][(wm + i * 16 + c16) * 128];
        i32x4 lo = *(const i32x4*)(rbase + (((quad * 2) ^ sw) * 16));
        i32x4 hi = *(const i32x4*)(rbase + (((quad * 2 + 1) ^ sw) * 16));
        i32x8 a; a[0]=lo[0]; a[1]=lo[1]; a[2]=lo[2]; a[3]=lo[3];
        a[4]=hi[0]; a[5]=hi[1]; a[6]=hi[2]; a[7]=hi[3];
        af[i] = a;
      }
#pragma unroll
      for (int j = 0; j < 4; j++) {
        const unsigned char* rbase = &Bs[cur][(wn + j * 16 + c16) * 128];
        i32x4 lo = *(const i32x4*)(rbase + (((quad * 2) ^ sw) * 16));
        i32x4 hi = *(const i32x4*)(rbase + (((quad * 2 + 1) ^ sw) * 16));
        i32x8 b; b[0]=lo[0]; b[1]=lo[1]; b[2]=lo[2]; b[3]=lo[3];
        b[4]=hi[0]; b[5]=hi[1]; b[6]=hi[2]; b[7]=hi[3];
        bf[j] = b;
      }
#pragma unroll
      for (int i = 0; i < 4; i++)
#pragma unroll
        for (int j = 0; j < 4; j++)
          acc[i][j] = __builtin_amdgcn_mfma_scale_f32_16x16x128_f8f6f4(
              af[i], bf[j], acc[i][j], 0 /*fmtA=fp8*/, 0 /*fmtB=fp8*/,
              0, sc1, 0, sc1);
    }
    __syncthreads();   // drains prefetch vmcnt (overlapped with compute above)
  }

  // epilogue: C/D layout col=lane&15, row=quad*4+reg (shape-determined);
  // scatter through rowlist, add bias
#pragma unroll
  for (int i = 0; i < 4; i++) {
    int rloc0 = wm + i * 16 + quad * 4;
#pragma unroll
    for (int r = 0; r < 4; r++) {
      int idx = rloc0 + r;
      if (rowbase + idx < cntg) {
        int orow = rl[rowbase + idx];
        float* orowp = out + (size_t)orow * L_DIM + n0;
#pragma unroll
        for (int j = 0; j < 4; j++) {
          int n = wn + j * 16 + c16;
          orowp[n] = acc[i][j][r] + bias[head * L_DIM + n0 + n];
        }
      }
    }
  }
}

extern "C" void kernel_launch(void* const* d_in, const int* in_sizes, int n_in,
                              void* d_out, int out_size, void* d_ws, size_t ws_size,
                              hipStream_t stream) {
  const float* hidden = (const float*)d_in[0];
  const float* W      = (const float*)d_in[1];
  const float* bias   = (const float*)d_in[2];
  const int* group    = (const int*)d_in[3];
  const int* labels   = (const int*)d_in[4];
  float* out = (float*)d_out;

  // ws layout: [cnt 64B][rowlist 5*8192*4B @256][Wb fp8 @256KB (5MB)][Hb fp8 @256KB+6MB (8MB)]
  char* ws = (char*)d_ws;
  int* cnt = (int*)ws;
  int* rowlist = (int*)(ws + 256);
  unsigned char* Wb = (unsigned char*)(ws + (1 << 18));
  unsigned char* Hb = (unsigned char*)(ws + (1 << 18) + (6u << 20));

  hipMemsetAsync(cnt, 0, 64, stream);
  k_bucket<<<B_ROWS / 256, 256, 0, stream>>>(group, cnt, rowlist);
  k_conv<<<512 + B_ROWS / 8, 256, 0, stream>>>(hidden, W, group, labels, Hb, Wb, out);
  k_gemm<<<dim3(L_DIM / 128, B_ROWS / 128, NH), 256, 0, stream>>>(Hb, Wb, bias, cnt, rowlist, out);
}

// Round 6
// 136.266 us; speedup vs baseline: 1.2433x; 1.2433x over previous
//
#include <hip/hip_runtime.h>
#include <stdint.h>

#define B_ROWS 8192
#define H_DIM 1024
#define L_DIM 1024
#define NH 5

typedef short bf16x8 __attribute__((ext_vector_type(8)));
typedef float f32x4 __attribute__((ext_vector_type(4)));

typedef const __attribute__((address_space(1))) unsigned int* gas_uint_ptr;
typedef __attribute__((address_space(3))) unsigned int* las_uint_ptr;

__device__ __forceinline__ unsigned short f2bf(float f) {
  union { float f; unsigned int u; } v; v.f = f;
  return (unsigned short)((v.u + 0x7FFFu + ((v.u >> 16) & 1u)) >> 16);
}

__device__ __forceinline__ void load_lds16(const void* gsrc, void* ldst) {
  __builtin_amdgcn_global_load_lds((gas_uint_ptr)(uintptr_t)gsrc,
                                   (las_uint_ptr)(uintptr_t)ldst, 16, 0, 0);
}

// ---- kernel 1: fused streaming convert + bucket ----
// blocks [0,512):     W fp32->bf16, grid-stride, 10 float4/thread
// blocks [512,1536):  8 rows/block; g==5 -> fill out with label, else hidden->bf16 Hb
// blocks [1536,1568): bucket rows by group (LDS-aggregated, 5 global atomics/block)
__global__ void k_conv(const float* __restrict__ hidden, const float* __restrict__ W,
                       const int* __restrict__ group, const int* __restrict__ labels,
                       int* __restrict__ cnt, int* __restrict__ rowlist,
                       unsigned short* __restrict__ Hb, unsigned short* __restrict__ Wb,
                       float* __restrict__ out) {
  const int blk = blockIdx.x;
  const int t = threadIdx.x;
  if (blk < 512) {
    const float4* src = (const float4*)W;
    ushort4* dst = (ushort4*)Wb;
#pragma unroll
    for (int i = 0; i < 10; i++) {
      int idx = (i * 512 + blk) * 256 + t;   // 512*256*10 = 1,310,720 float4 = all of W
      float4 w = src[idx];
      ushort4 o;
      o.x = f2bf(w.x); o.y = f2bf(w.y); o.z = f2bf(w.z); o.w = f2bf(w.w);
      dst[idx] = o;
    }
  } else if (blk < 1536) {
    const int rb = (blk - 512) * 8;
    int gs[8];
#pragma unroll
    for (int r = 0; r < 8; r++) gs[r] = group[rb + r];   // independent loads up front
#pragma unroll
    for (int r = 0; r < 8; r++) {
      int row = rb + r;
      if (gs[r] == NH) {
        float v = (float)labels[row];
        ((float4*)(out + (size_t)row * L_DIM))[t] = make_float4(v, v, v, v);
      } else {
        float4 h = ((const float4*)(hidden + (size_t)row * H_DIM))[t];
        ushort4 o;
        o.x = f2bf(h.x); o.y = f2bf(h.y); o.z = f2bf(h.z); o.w = f2bf(h.w);
        ((ushort4*)(Hb + (size_t)row * H_DIM))[t] = o;
      }
    }
  } else {
    __shared__ int lcnt[NH];
    __shared__ int lbase[NH];
    if (t < NH) lcnt[t] = 0;
    __syncthreads();
    int b = (blk - 1536) * 256 + t;
    int g = group[b];
    int lpos = -1;
    if (g < NH) lpos = atomicAdd(&lcnt[g], 1);
    __syncthreads();
    if (t < NH) lbase[t] = atomicAdd(&cnt[t], lcnt[t]);
    __syncthreads();
    if (g < NH) rowlist[g * B_ROWS + lbase[g] + lpos] = b;
  }
}

// ---- kernel 2: bucketed bf16 MFMA GEMM, 128Mx64N tile, BK=64, double-buffered ----
// 880 active blocks (vs 440 at 128x128) and 48 KB LDS -> 3 blocks/CU: latency
// hiding through block-level parallelism. 4 waves (2Mx2N), each wave 64x32 =
// 4x2 frags of 16x16x32 bf16. LDS XOR-swizzle on 16B chunks (bank spread).
// Double buffer: stage kt+1 before computing kt so the barrier's vmcnt drain
// overlaps the MFMA+ds_read phase.
__global__ __launch_bounds__(256, 3)
void k_gemm(const unsigned short* __restrict__ Hb, const unsigned short* __restrict__ Wb,
            const float* __restrict__ bias, const int* __restrict__ cnt,
            const int* __restrict__ rowlist, float* __restrict__ out) {
  const int head = blockIdx.z;
  const int cntg = cnt[head];
  const int rowbase = blockIdx.y * 128;
  if (rowbase >= cntg) return;
  const int n0 = blockIdx.x * 64;

  __shared__ __align__(16) unsigned short As[2][128 * 64];  // 32 KB
  __shared__ __align__(16) unsigned short Bs[2][64 * 64];   // 16 KB

  const int t = threadIdx.x;
  const int wave = t >> 6, lane = t & 63;
  const int quad = lane >> 4, c16 = lane & 15;
  const int wm = (wave & 1) * 64, wn = (wave >> 1) * 32;

  const unsigned short* Wg = Wb + (size_t)head * L_DIM * H_DIM;
  const int* rl = rowlist + head * B_ROWS;

  // per-thread staging sources (loop-invariant; +kt per iteration)
  const unsigned short* srcA[4];
  const unsigned short* srcB[2];
  int ldsoA[4], ldsoB[2];
#pragma unroll
  for (int p = 0; p < 4; p++) {          // A: 1024 16B chunks (128 rows x 8)
    int c = p * 256 + t;
    int row = c >> 3;
    int ks = ((c & 7) ^ (row & 7)) * 8;  // XOR-swizzled source column (shorts)
    int idx = rowbase + row;
    idx = idx < cntg ? idx : cntg - 1;   // clamp into valid rowlist entries
    srcA[p] = Hb + (size_t)rl[idx] * H_DIM + ks;
    ldsoA[p] = c * 8;
  }
#pragma unroll
  for (int p = 0; p < 2; p++) {          // B: 512 16B chunks (64 rows x 8)
    int c = p * 256 + t;
    int row = c >> 3;
    int ks = ((c & 7) ^ (row & 7)) * 8;
    srcB[p] = Wg + (size_t)(n0 + row) * H_DIM + ks;
    ldsoB[p] = c * 8;
  }

  f32x4 acc[4][2] = {};

  // prologue: stage K-tile 0
#pragma unroll
  for (int p = 0; p < 4; p++) load_lds16(srcA[p], &As[0][ldsoA[p]]);
#pragma unroll
  for (int p = 0; p < 2; p++) load_lds16(srcB[p], &Bs[0][ldsoB[p]]);
  __syncthreads();

  for (int kt = 0; kt < H_DIM; kt += 64) {
    const int cur = (kt >> 6) & 1;
    if (kt + 64 < H_DIM) {
      const int nxt = cur ^ 1;
#pragma unroll
      for (int p = 0; p < 4; p++) load_lds16(srcA[p] + kt + 64, &As[nxt][ldsoA[p]]);
#pragma unroll
      for (int p = 0; p < 2; p++) load_lds16(srcB[p] + kt + 64, &Bs[nxt][ldsoB[p]]);
    }
#pragma unroll
    for (int kk = 0; kk < 64; kk += 32) {
      bf16x8 af[4], bf[2];
      const int sw = c16 & 7;             // row&7 == c16&7 for all frag rows
      const int colb = (kk >> 4) << 1;    // kk=0 -> chunks 0..3, kk=32 -> 4..7
      const int cl = (colb + quad) ^ sw;
#pragma unroll
      for (int i = 0; i < 4; i++) {
        int row = wm + i * 16 + c16;
        af[i] = *(const bf16x8*)(&As[cur][row * 64 + cl * 8]);
      }
#pragma unroll
      for (int j = 0; j < 2; j++) {
        int row = wn + j * 16 + c16;
        bf[j] = *(const bf16x8*)(&Bs[cur][row * 64 + cl * 8]);
      }
#pragma unroll
      for (int i = 0; i < 4; i++)
#pragma unroll
        for (int j = 0; j < 2; j++)
          acc[i][j] = __builtin_amdgcn_mfma_f32_16x16x32_bf16(af[i], bf[j], acc[i][j], 0, 0, 0);
    }
    __syncthreads();   // drains prefetch vmcnt (overlapped with compute above)
  }

  // epilogue: C/D layout col=lane&15, row=quad*4+reg; scatter through rowlist, add bias
#pragma unroll
  for (int i = 0; i < 4; i++) {
    int rloc0 = wm + i * 16 + quad * 4;
#pragma unroll
    for (int r = 0; r < 4; r++) {
      int idx = rloc0 + r;
      if (rowbase + idx < cntg) {
        int orow = rl[rowbase + idx];
        float* orowp = out + (size_t)orow * L_DIM + n0;
#pragma unroll
        for (int j = 0; j < 2; j++) {
          int n = wn + j * 16 + c16;
          orowp[n] = acc[i][j][r] + bias[head * L_DIM + n0 + n];
        }
      }
    }
  }
}

extern "C" void kernel_launch(void* const* d_in, const int* in_sizes, int n_in,
                              void* d_out, int out_size, void* d_ws, size_t ws_size,
                              hipStream_t stream) {
  const float* hidden = (const float*)d_in[0];
  const float* W      = (const float*)d_in[1];
  const float* bias   = (const float*)d_in[2];
  const int* group    = (const int*)d_in[3];
  const int* labels   = (const int*)d_in[4];
  float* out = (float*)d_out;

  // ws layout: [cnt 64B][rowlist 5*8192*4B @256][Wb bf16 @256KB][Hb bf16 after Wb]
  char* ws = (char*)d_ws;
  int* cnt = (int*)ws;
  int* rowlist = (int*)(ws + 256);
  unsigned short* Wb = (unsigned short*)(ws + (1 << 18));
  unsigned short* Hb = (unsigned short*)(ws + (1 << 18) + (size_t)NH * L_DIM * H_DIM * 2);

  hipMemsetAsync(cnt, 0, 64, stream);
  k_conv<<<1568, 256, 0, stream>>>(hidden, W, group, labels, cnt, rowlist, Hb, Wb, out);
  k_gemm<<<dim3(L_DIM / 64, B_ROWS / 128, NH), 256, 0, stream>>>(Hb, Wb, bias, cnt, rowlist, out);
}

// Round 7
// 133.107 us; speedup vs baseline: 1.2728x; 1.0237x over previous
//
#include <hip/hip_runtime.h>
#include <stdint.h>

#define B_ROWS 8192
#define H_DIM 1024
#define L_DIM 1024
#define NH 5

typedef short bf16x8 __attribute__((ext_vector_type(8)));
typedef float f32x4 __attribute__((ext_vector_type(4)));

typedef const __attribute__((address_space(1))) unsigned int* gas_uint_ptr;
typedef __attribute__((address_space(3))) unsigned int* las_uint_ptr;

__device__ __forceinline__ unsigned short f2bf(float f) {
  union { float f; unsigned int u; } v; v.f = f;
  return (unsigned short)((v.u + 0x7FFFu + ((v.u >> 16) & 1u)) >> 16);
}

__device__ __forceinline__ void load_lds16(const void* gsrc, void* ldst) {
  __builtin_amdgcn_global_load_lds((gas_uint_ptr)(uintptr_t)gsrc,
                                   (las_uint_ptr)(uintptr_t)ldst, 16, 0, 0);
}

// ---- kernel 1: fused streaming convert + bucket ----
// blocks [0,512):     W fp32->bf16, grid-stride, 10 float4/thread
// blocks [512,1536):  8 rows/block; g==5 -> fill out with label, else hidden->bf16 Hb
// blocks [1536,1568): bucket rows by group (LDS-aggregated, 5 global atomics/block)
__global__ void k_conv(const float* __restrict__ hidden, const float* __restrict__ W,
                       const int* __restrict__ group, const int* __restrict__ labels,
                       int* __restrict__ cnt, int* __restrict__ rowlist,
                       unsigned short* __restrict__ Hb, unsigned short* __restrict__ Wb,
                       float* __restrict__ out) {
  const int blk = blockIdx.x;
  const int t = threadIdx.x;
  if (blk < 512) {
    const float4* src = (const float4*)W;
    ushort4* dst = (ushort4*)Wb;
#pragma unroll
    for (int i = 0; i < 10; i++) {
      int idx = (i * 512 + blk) * 256 + t;   // 512*256*10 = 1,310,720 float4 = all of W
      float4 w = src[idx];
      ushort4 o;
      o.x = f2bf(w.x); o.y = f2bf(w.y); o.z = f2bf(w.z); o.w = f2bf(w.w);
      dst[idx] = o;
    }
  } else if (blk < 1536) {
    const int rb = (blk - 512) * 8;
    int gs[8];
#pragma unroll
    for (int r = 0; r < 8; r++) gs[r] = group[rb + r];   // independent loads up front
#pragma unroll
    for (int r = 0; r < 8; r++) {
      int row = rb + r;
      if (gs[r] == NH) {
        float v = (float)labels[row];
        ((float4*)(out + (size_t)row * L_DIM))[t] = make_float4(v, v, v, v);
      } else {
        float4 h = ((const float4*)(hidden + (size_t)row * H_DIM))[t];
        ushort4 o;
        o.x = f2bf(h.x); o.y = f2bf(h.y); o.z = f2bf(h.z); o.w = f2bf(h.w);
        ((ushort4*)(Hb + (size_t)row * H_DIM))[t] = o;
      }
    }
  } else {
    __shared__ int lcnt[NH];
    __shared__ int lbase[NH];
    if (t < NH) lcnt[t] = 0;
    __syncthreads();
    int b = (blk - 1536) * 256 + t;
    int g = group[b];
    int lpos = -1;
    if (g < NH) lpos = atomicAdd(&lcnt[g], 1);
    __syncthreads();
    if (t < NH) lbase[t] = atomicAdd(&cnt[t], lcnt[t]);
    __syncthreads();
    if (g < NH) rowlist[g * B_ROWS + lbase[g] + lpos] = b;
  }
}

// ---- kernel 2: bucketed bf16 MFMA GEMM, 128x128 tile, BK=64, SINGLE-buffered ----
// Round-4's 128x128 reuse profile (best traffic) + 3 blocks/CU occupancy:
// single buffer = 32 KB LDS, launch_bounds(256,3) -> 3 waves/EU (140 regs/wave
// fits the 170 budget). m97-style 2-barrier K-loop; inter-block overlap (m114)
// hides the vmcnt drain instead of explicit dbuf (which forced 2 blocks/CU).
// LDS XOR-swizzle on 16B chunks: col cl holds global col cl ^ (row&7).
__global__ __launch_bounds__(256, 3)
void k_gemm(const unsigned short* __restrict__ Hb, const unsigned short* __restrict__ Wb,
            const float* __restrict__ bias, const int* __restrict__ cnt,
            const int* __restrict__ rowlist, float* __restrict__ out) {
  const int head = blockIdx.z;
  const int cntg = cnt[head];
  const int rowbase = blockIdx.y * 128;
  if (rowbase >= cntg) return;
  const int n0 = blockIdx.x * 128;

  __shared__ __align__(16) unsigned short As[128 * 64];  // 16 KB
  __shared__ __align__(16) unsigned short Bs[128 * 64];  // 16 KB

  const int t = threadIdx.x;
  const int wave = t >> 6, lane = t & 63;
  const int quad = lane >> 4, c16 = lane & 15;
  const int wm = (wave & 1) * 64, wn = (wave >> 1) * 64;

  const unsigned short* Wg = Wb + (size_t)head * L_DIM * H_DIM;
  const int* rl = rowlist + head * B_ROWS;

  // per-thread staging sources (loop-invariant; +kt per iteration)
  const unsigned short* srcA[4];
  const unsigned short* srcB[4];
  int ldso[4];
#pragma unroll
  for (int p = 0; p < 4; p++) {
    int c = p * 256 + t;                  // 16B chunk id 0..1023
    int row = c >> 3;
    int ks = ((c & 7) ^ (row & 7)) * 8;   // XOR-swizzled source column (shorts)
    int idx = rowbase + row;
    idx = idx < cntg ? idx : cntg - 1;    // clamp into valid rowlist entries
    srcA[p] = Hb + (size_t)rl[idx] * H_DIM + ks;
    srcB[p] = Wg + (size_t)(n0 + row) * H_DIM + ks;
    ldso[p] = c * 8;                      // lane-linear LDS dst (shorts)
  }

  f32x4 acc[4][4] = {};

  for (int kt = 0; kt < H_DIM; kt += 64) {
    if (kt) __syncthreads();              // previous compute done before overwrite
#pragma unroll
    for (int p = 0; p < 4; p++) {
      load_lds16(srcA[p] + kt, &As[ldso[p]]);
      load_lds16(srcB[p] + kt, &Bs[ldso[p]]);
    }
    __syncthreads();                      // staging visible (vmcnt drain here)
#pragma unroll
    for (int kk = 0; kk < 64; kk += 32) {
      bf16x8 af[4], bf[4];
      const int sw = c16 & 7;             // row&7 == c16&7 for all frag rows
      const int colb = (kk >> 4) << 1;    // kk=0 -> chunks 0..3, kk=32 -> 4..7
      const int cl = (colb + quad) ^ sw;
#pragma unroll
      for (int i = 0; i < 4; i++) {
        int row = wm + i * 16 + c16;
        af[i] = *(const bf16x8*)(&As[row * 64 + cl * 8]);
      }
#pragma unroll
      for (int j = 0; j < 4; j++) {
        int row = wn + j * 16 + c16;
        bf[j] = *(const bf16x8*)(&Bs[row * 64 + cl * 8]);
      }
#pragma unroll
      for (int i = 0; i < 4; i++)
#pragma unroll
        for (int j = 0; j < 4; j++)
          acc[i][j] = __builtin_amdgcn_mfma_f32_16x16x32_bf16(af[i], bf[j], acc[i][j], 0, 0, 0);
    }
  }

  // epilogue: C/D layout col=lane&15, row=quad*4+reg; scatter through rowlist, add bias
#pragma unroll
  for (int i = 0; i < 4; i++) {
    int rloc0 = wm + i * 16 + quad * 4;
#pragma unroll
    for (int r = 0; r < 4; r++) {
      int idx = rloc0 + r;
      if (rowbase + idx < cntg) {
        int orow = rl[rowbase + idx];
        float* orowp = out + (size_t)orow * L_DIM + n0;
#pragma unroll
        for (int j = 0; j < 4; j++) {
          int n = wn + j * 16 + c16;
          orowp[n] = acc[i][j][r] + bias[head * L_DIM + n0 + n];
        }
      }
    }
  }
}

extern "C" void kernel_launch(void* const* d_in, const int* in_sizes, int n_in,
                              void* d_out, int out_size, void* d_ws, size_t ws_size,
                              hipStream_t stream) {
  const float* hidden = (const float*)d_in[0];
  const float* W      = (const float*)d_in[1];
  const float* bias   = (const float*)d_in[2];
  const int* group    = (const int*)d_in[3];
  const int* labels   = (const int*)d_in[4];
  float* out = (float*)d_out;

  // ws layout: [cnt 64B][rowlist 5*8192*4B @256][Wb bf16 @256KB][Hb bf16 after Wb]
  char* ws = (char*)d_ws;
  int* cnt = (int*)ws;
  int* rowlist = (int*)(ws + 256);
  unsigned short* Wb = (unsigned short*)(ws + (1 << 18));
  unsigned short* Hb = (unsigned short*)(ws + (1 << 18) + (size_t)NH * L_DIM * H_DIM * 2);

  hipMemsetAsync(cnt, 0, 64, stream);
  k_conv<<<1568, 256, 0, stream>>>(hidden, W, group, labels, cnt, rowlist, Hb, Wb, out);
  k_gemm<<<dim3(L_DIM / 128, B_ROWS / 128, NH), 256, 0, stream>>>(Hb, Wb, bias, cnt, rowlist, out);
}

// Round 8
// 128.604 us; speedup vs baseline: 1.3174x; 1.0350x over previous
//
#include <hip/hip_runtime.h>
#include <stdint.h>

#define B_ROWS 8192
#define H_DIM 1024
#define L_DIM 1024
#define NH 5

typedef short bf16x8 __attribute__((ext_vector_type(8)));
typedef float f32x4 __attribute__((ext_vector_type(4)));

typedef const __attribute__((address_space(1))) unsigned int* gas_uint_ptr;
typedef __attribute__((address_space(3))) unsigned int* las_uint_ptr;

__device__ __forceinline__ unsigned short f2bf(float f) {
  union { float f; unsigned int u; } v; v.f = f;
  return (unsigned short)((v.u + 0x7FFFu + ((v.u >> 16) & 1u)) >> 16);
}

__device__ __forceinline__ void load_lds16(const void* gsrc, void* ldst) {
  __builtin_amdgcn_global_load_lds((gas_uint_ptr)(uintptr_t)gsrc,
                                   (las_uint_ptr)(uintptr_t)ldst, 16, 0, 0);
}

// ---- kernel 1: fused streaming convert + bucket (round-7, kept) ----
// blocks [0,512):     W fp32->bf16, grid-stride, 10 float4/thread
// blocks [512,1536):  8 rows/block; g==5 -> fill out with label, else hidden->bf16 Hb
// blocks [1536,1568): bucket rows by group (LDS-aggregated, 5 global atomics/block)
__global__ void k_conv(const float* __restrict__ hidden, const float* __restrict__ W,
                       const int* __restrict__ group, const int* __restrict__ labels,
                       int* __restrict__ cnt, int* __restrict__ rowlist,
                       unsigned short* __restrict__ Hb, unsigned short* __restrict__ Wb,
                       float* __restrict__ out) {
  const int blk = blockIdx.x;
  const int t = threadIdx.x;
  if (blk < 512) {
    const float4* src = (const float4*)W;
    ushort4* dst = (ushort4*)Wb;
#pragma unroll
    for (int i = 0; i < 10; i++) {
      int idx = (i * 512 + blk) * 256 + t;   // 512*256*10 = 1,310,720 float4 = all of W
      float4 w = src[idx];
      ushort4 o;
      o.x = f2bf(w.x); o.y = f2bf(w.y); o.z = f2bf(w.z); o.w = f2bf(w.w);
      dst[idx] = o;
    }
  } else if (blk < 1536) {
    const int rb = (blk - 512) * 8;
    int gs[8];
#pragma unroll
    for (int r = 0; r < 8; r++) gs[r] = group[rb + r];   // independent loads up front
#pragma unroll
    for (int r = 0; r < 8; r++) {
      int row = rb + r;
      if (gs[r] == NH) {
        float v = (float)labels[row];
        ((float4*)(out + (size_t)row * L_DIM))[t] = make_float4(v, v, v, v);
      } else {
        float4 h = ((const float4*)(hidden + (size_t)row * H_DIM))[t];
        ushort4 o;
        o.x = f2bf(h.x); o.y = f2bf(h.y); o.z = f2bf(h.z); o.w = f2bf(h.w);
        ((ushort4*)(Hb + (size_t)row * H_DIM))[t] = o;
      }
    }
  } else {
    __shared__ int lcnt[NH];
    __shared__ int lbase[NH];
    if (t < NH) lcnt[t] = 0;
    __syncthreads();
    int b = (blk - 1536) * 256 + t;
    int g = group[b];
    int lpos = -1;
    if (g < NH) lpos = atomicAdd(&lcnt[g], 1);
    __syncthreads();
    if (t < NH) lbase[t] = atomicAdd(&cnt[t], lcnt[t]);
    __syncthreads();
    if (g < NH) rowlist[g * B_ROWS + lbase[g] + lpos] = b;
  }
}

// ---- kernel 2: bucketed bf16 MFMA GEMM (round-4 config, the measured best) ----
// 128x128 tile, BK=64, double-buffered LDS (64 KB -> 2 blocks/CU), 4 waves
// (2x2), each wave 4x4 frags of 16x16x32 bf16. LDS XOR-swizzle on 16B chunks
// (col cl holds global col cl ^ (row&7)) -> conflict-free ds_read_b128.
// Prefetch kt+1 before computing kt: the barrier's vmcnt(0) drain overlaps the
// whole MFMA+ds_read phase. Measured better than sbuf@3blk (R7) and
// 128x64@3blk (R6): with only ~440 blocks there is no dispatch queue, so
// exposed per-barrier latency dominates over co-residency count.
__global__ __launch_bounds__(256, 2)
void k_gemm(const unsigned short* __restrict__ Hb, const unsigned short* __restrict__ Wb,
            const float* __restrict__ bias, const int* __restrict__ cnt,
            const int* __restrict__ rowlist, float* __restrict__ out) {
  const int head = blockIdx.z;
  const int cntg = cnt[head];
  const int rowbase = blockIdx.y * 128;
  if (rowbase >= cntg) return;
  const int n0 = blockIdx.x * 128;

  __shared__ __align__(16) unsigned short As[2][128 * 64];
  __shared__ __align__(16) unsigned short Bs[2][128 * 64];

  const int t = threadIdx.x;
  const int wave = t >> 6, lane = t & 63;
  const int quad = lane >> 4, c16 = lane & 15;
  const int wm = (wave & 1) * 64, wn = (wave >> 1) * 64;

  const unsigned short* Wg = Wb + (size_t)head * L_DIM * H_DIM;
  const int* rl = rowlist + head * B_ROWS;

  // per-thread staging sources (loop-invariant; +kt per iteration)
  const unsigned short* srcA[4];
  const unsigned short* srcB[4];
  int ldso[4];
#pragma unroll
  for (int p = 0; p < 4; p++) {
    int c = p * 256 + t;                  // 16B chunk id 0..1023
    int row = c >> 3;
    int ks = ((c & 7) ^ (row & 7)) * 8;   // XOR-swizzled source column (shorts)
    int idx = rowbase + row;
    idx = idx < cntg ? idx : cntg - 1;    // clamp into valid rowlist entries
    srcA[p] = Hb + (size_t)rl[idx] * H_DIM + ks;
    srcB[p] = Wg + (size_t)(n0 + row) * H_DIM + ks;
    ldso[p] = c * 8;                      // lane-linear LDS dst (shorts)
  }

  f32x4 acc[4][4] = {};

  // prologue: stage tile 0
#pragma unroll
  for (int p = 0; p < 4; p++) {
    load_lds16(srcA[p], &As[0][ldso[p]]);
    load_lds16(srcB[p], &Bs[0][ldso[p]]);
  }
  __syncthreads();

  for (int kt = 0; kt < H_DIM; kt += 64) {
    const int cur = (kt >> 6) & 1;
    if (kt + 64 < H_DIM) {
      const int nxt = cur ^ 1;
#pragma unroll
      for (int p = 0; p < 4; p++) {
        load_lds16(srcA[p] + kt + 64, &As[nxt][ldso[p]]);
        load_lds16(srcB[p] + kt + 64, &Bs[nxt][ldso[p]]);
      }
    }
#pragma unroll
    for (int kk = 0; kk < 64; kk += 32) {
      bf16x8 af[4], bf[4];
      const int sw = c16 & 7;             // row&7 == c16&7 for all frag rows
      const int colb = (kk >> 4) << 1;    // kk=0 -> chunks 0..3, kk=32 -> 4..7
      const int cl = (colb + quad) ^ sw;
#pragma unroll
      for (int i = 0; i < 4; i++) {
        int row = wm + i * 16 + c16;
        af[i] = *(const bf16x8*)(&As[cur][row * 64 + cl * 8]);
      }
#pragma unroll
      for (int j = 0; j < 4; j++) {
        int row = wn + j * 16 + c16;
        bf[j] = *(const bf16x8*)(&Bs[cur][row * 64 + cl * 8]);
      }
#pragma unroll
      for (int i = 0; i < 4; i++)
#pragma unroll
        for (int j = 0; j < 4; j++)
          acc[i][j] = __builtin_amdgcn_mfma_f32_16x16x32_bf16(af[i], bf[j], acc[i][j], 0, 0, 0);
    }
    __syncthreads();   // drains prefetch vmcnt (overlapped with compute above)
  }

  // epilogue: C/D layout col=lane&15, row=quad*4+reg; scatter through rowlist, add bias
#pragma unroll
  for (int i = 0; i < 4; i++) {
    int rloc0 = wm + i * 16 + quad * 4;
#pragma unroll
    for (int r = 0; r < 4; r++) {
      int idx = rloc0 + r;
      if (rowbase + idx < cntg) {
        int orow = rl[rowbase + idx];
        float* orowp = out + (size_t)orow * L_DIM + n0;
#pragma unroll
        for (int j = 0; j < 4; j++) {
          int n = wn + j * 16 + c16;
          orowp[n] = acc[i][j][r] + bias[head * L_DIM + n0 + n];
        }
      }
    }
  }
}

extern "C" void kernel_launch(void* const* d_in, const int* in_sizes, int n_in,
                              void* d_out, int out_size, void* d_ws, size_t ws_size,
                              hipStream_t stream) {
  const float* hidden = (const float*)d_in[0];
  const float* W      = (const float*)d_in[1];
  const float* bias   = (const float*)d_in[2];
  const int* group    = (const int*)d_in[3];
  const int* labels   = (const int*)d_in[4];
  float* out = (float*)d_out;

  // ws layout: [cnt 64B][rowlist 5*8192*4B @256][Wb bf16 @256KB][Hb bf16 after Wb]
  char* ws = (char*)d_ws;
  int* cnt = (int*)ws;
  int* rowlist = (int*)(ws + 256);
  unsigned short* Wb = (unsigned short*)(ws + (1 << 18));
  unsigned short* Hb = (unsigned short*)(ws + (1 << 18) + (size_t)NH * L_DIM * H_DIM * 2);

  hipMemsetAsync(cnt, 0, 64, stream);
  k_conv<<<1568, 256, 0, stream>>>(hidden, W, group, labels, cnt, rowlist, Hb, Wb, out);
  k_gemm<<<dim3(L_DIM / 128, B_ROWS / 128, NH), 256, 0, stream>>>(Hb, Wb, bias, cnt, rowlist, out);
}